// Round 2
// baseline (359.005 us; speedup 1.0000x reference)
//
#include <hip/hip_runtime.h>
#include <math.h>

#define N_TOK 2048
#define NDIM 512
#define HEADS 8
#define NUM_KEYS 256
#define DIM_KEY 256
#define TOPK 16
#define QCOLS 4096  // 2*HEADS*DIM_KEY

// ---------------- K1: M[c, p*2048+h*256+k] = sum_d Wq[c, p*2048+h*256+d] * keys[h,k,p,d]
__global__ __launch_bounds__(256) void k1_combine(const float* __restrict__ Wq,
                                                  const float* __restrict__ keys,
                                                  float* __restrict__ M) {
    __shared__ float As[16][64];
    __shared__ float Bs[16][64];
    const int ph = blockIdx.z;       // p*8 + h
    const int p = ph >> 3, h = ph & 7;
    const int off = p * 2048 + h * 256;
    const int c0 = blockIdx.x * 64;
    const int k0 = blockIdx.y * 64;
    const int tid = threadIdx.x;
    const int lr = tid >> 2;
    const int ld4 = (tid & 3) * 4;
    const int tr = tid >> 4, tc = tid & 15;
    float acc[4][4] = {};
    for (int d0 = 0; d0 < DIM_KEY; d0 += 16) {
        float4 av = *reinterpret_cast<const float4*>(&Wq[(size_t)(c0 + lr) * QCOLS + off + d0 + ld4]);
        float4 bv = *reinterpret_cast<const float4*>(&keys[(size_t)((h * 256 + (k0 + lr)) * 2 + p) * 256 + d0 + ld4]);
        __syncthreads();
        As[ld4 + 0][lr] = av.x; As[ld4 + 1][lr] = av.y; As[ld4 + 2][lr] = av.z; As[ld4 + 3][lr] = av.w;
        Bs[ld4 + 0][lr] = bv.x; Bs[ld4 + 1][lr] = bv.y; Bs[ld4 + 2][lr] = bv.z; Bs[ld4 + 3][lr] = bv.w;
        __syncthreads();
        #pragma unroll
        for (int kk = 0; kk < 16; ++kk) {
            float4 a = *reinterpret_cast<const float4*>(&As[kk][tr * 4]);
            float4 b = *reinterpret_cast<const float4*>(&Bs[kk][tc * 4]);
            float aa[4] = {a.x, a.y, a.z, a.w}, bb[4] = {b.x, b.y, b.z, b.w};
            #pragma unroll
            for (int i = 0; i < 4; ++i)
                #pragma unroll
                for (int j = 0; j < 4; ++j) acc[i][j] += aa[i] * bb[j];
        }
    }
    #pragma unroll
    for (int i = 0; i < 4; ++i) {
        float4 o = {acc[i][0], acc[i][1], acc[i][2], acc[i][3]};
        *reinterpret_cast<float4*>(&M[(size_t)(c0 + tr * 4 + i) * QCOLS + off + k0 + tc * 4]) = o;
    }
}

// ---------------- K2: sim[2048,4096] = x[2048,512] @ M[512,4096], fp32 VALU GEMM
__global__ __launch_bounds__(256) void k2_gemm(const float* __restrict__ A,
                                               const float* __restrict__ B,
                                               float* __restrict__ C) {
    __shared__ float As[8][128];
    __shared__ float Bs[8][128];
    const int row0 = blockIdx.x * 128;
    const int col0 = blockIdx.y * 128;
    const int tid = threadIdx.x;
    const int ar = tid >> 1, ak = (tid & 1) * 4;
    const int bk = tid >> 5, bc = (tid & 31) * 4;
    const int tr = tid >> 4, tc = tid & 15;
    float acc[8][8] = {};
    for (int k0 = 0; k0 < NDIM; k0 += 8) {
        float4 av = *reinterpret_cast<const float4*>(&A[(size_t)(row0 + ar) * NDIM + k0 + ak]);
        float4 bv = *reinterpret_cast<const float4*>(&B[(size_t)(k0 + bk) * QCOLS + col0 + bc]);
        __syncthreads();
        As[ak + 0][ar] = av.x; As[ak + 1][ar] = av.y; As[ak + 2][ar] = av.z; As[ak + 3][ar] = av.w;
        *reinterpret_cast<float4*>(&Bs[bk][bc]) = bv;
        __syncthreads();
        #pragma unroll
        for (int kk = 0; kk < 8; ++kk) {
            float a[8], b[8];
            *(float4*)&a[0] = *(const float4*)&As[kk][tr * 8];
            *(float4*)&a[4] = *(const float4*)&As[kk][tr * 8 + 4];
            *(float4*)&b[0] = *(const float4*)&Bs[kk][tc * 8];
            *(float4*)&b[4] = *(const float4*)&Bs[kk][tc * 8 + 4];
            #pragma unroll
            for (int i = 0; i < 8; ++i)
                #pragma unroll
                for (int j = 0; j < 8; ++j) acc[i][j] += a[i] * b[j];
        }
    }
    #pragma unroll
    for (int i = 0; i < 8; ++i) {
        float* cp = &C[(size_t)(row0 + tr * 8 + i) * QCOLS + col0 + tc * 8];
        float4 o0 = {acc[i][0], acc[i][1], acc[i][2], acc[i][3]};
        float4 o1 = {acc[i][4], acc[i][5], acc[i][6], acc[i][7]};
        *(float4*)cp = o0;
        *(float4*)(cp + 4) = o1;
    }
}

// ---------------- K3 v2: 4 (n,h) pairs per wave, 16-lane groups.
// Candidate table for combined top-16: all (i,j) with (i+1)*(j+1) <= 16 (50 real,
// padded to 64 with (15,15) which can never rank < 16). Packed (i<<4)|j per byte,
// word per lane-in-group (4 slots each).
__device__ const unsigned int PK_TBL[16] = {
    0x03020100u, 0x07060504u, 0x0B0A0908u, 0x0F0E0D0Cu,
    0x13121110u, 0x17161514u, 0x23222120u, 0x32313024u,
    0x42414033u, 0x61605150u, 0x90807170u, 0xD0C0B0A0u,
    0xFFFFF0E0u, 0xFFFFFFFFu, 0xFFFFFFFFu, 0xFFFFFFFFu
};

__global__ __launch_bounds__(256, 4) void k3_topk(const float* __restrict__ sim,
                                                  const float* __restrict__ x,
                                                  const float* __restrict__ down,
                                                  int* __restrict__ idx_out,
                                                  float* __restrict__ w_out) {
    __shared__ unsigned long long ckey[4][4][65];  // [wave][group][64 keys (+pad)]
    __shared__ float winv[4][4][16];
    __shared__ int   winf[4][4][16];

    const int tid = threadIdx.x;
    const int wv = tid >> 6;
    const int lane = tid & 63;
    const int g = lane >> 4;        // group (pair) within wave
    const int lam = lane & 15;      // lane within group
    const int wg = blockIdx.x * 4 + wv;  // 0..4095
    const int pair = wg * 4 + g;         // 0..16383 ; all 4 pairs share n
    const int n = pair >> 3;
    const int h = pair & 7;

    // ---------- phase 1: per-p sorted top-16 values (keep0 = sx[lam], keep1 = sy[lam])
    float keep0 = 0.f, keep1 = 0.f;
    #pragma unroll
    for (int p = 0; p < 2; ++p) {
        const float* s = sim + (size_t)n * QCOLS + p * 2048 + h * 256 + lam * 16;
        float v[16];
        #pragma unroll
        for (int c = 0; c < 4; ++c) {
            float4 t = *reinterpret_cast<const float4*>(s + c * 4);
            v[c * 4 + 0] = t.x; v[c * 4 + 1] = t.y; v[c * 4 + 2] = t.z; v[c * 4 + 3] = t.w;
        }
        float keep = 0.f;
        #pragma unroll
        for (int r = 0; r < 16; ++r) {
            // local argmax tree over the lane's 16 values (lowest pos wins ties)
            float tv[16]; int ti[16];
            #pragma unroll
            for (int t = 0; t < 16; ++t) { tv[t] = v[t]; ti[t] = lam * 16 + t; }
            #pragma unroll
            for (int wdt = 8; wdt >= 1; wdt >>= 1)
                #pragma unroll
                for (int t = 0; t < wdt; ++t)
                    if (tv[t + wdt] > tv[t] || (tv[t + wdt] == tv[t] && ti[t + wdt] < ti[t])) {
                        tv[t] = tv[t + wdt]; ti[t] = ti[t + wdt];
                    }
            float mv = tv[0]; int mi = ti[0];
            // 4-step butterfly across the 16-lane group
            #pragma unroll
            for (int off = 1; off < 16; off <<= 1) {
                float ov = __shfl_xor(mv, off);
                int   oi = __shfl_xor(mi, off);
                if (ov > mv || (ov == mv && oi < mi)) { mv = ov; mi = oi; }
            }
            if (lam == r) keep = mv;
            #pragma unroll
            for (int t = 0; t < 16; ++t)
                if (lam * 16 + t == mi) v[t] = -INFINITY;
        }
        if (p == 0) keep0 = keep; else keep1 = keep;
    }

    // ---------- phase 2: combined top-16 over 50 monotone-matrix candidates
    const unsigned int tw = PK_TBL[lam];
    float myval[4]; int myflat[4]; unsigned long long mykey[4]; int myrank[4] = {0, 0, 0, 0};
    #pragma unroll
    for (int u = 0; u < 4; ++u) {
        const int b = (tw >> (8 * u)) & 0xFF;
        const int ii = b >> 4, jj = b & 15;
        const float sxi = __shfl(keep0, (g << 4) | ii);
        const float syj = __shfl(keep1, (g << 4) | jj);
        const float val = sxi + syj;
        const int flat = ii * 16 + jj;
        const unsigned int uv = __float_as_uint(val);
        const unsigned int mo = (uv & 0x80000000u) ? ~uv : (uv | 0x80000000u);
        const unsigned long long key =
            ((unsigned long long)mo << 8) | (unsigned long long)(255 - flat);
        ckey[wv][g][lam * 4 + u] = key;
        myval[u] = val; myflat[u] = flat; mykey[u] = key;
    }
    __syncthreads();
    #pragma unroll
    for (int k = 0; k < 64; ++k) {
        const unsigned long long kk = ckey[wv][g][k];
        #pragma unroll
        for (int u = 0; u < 4; ++u) myrank[u] += (kk > mykey[u]) ? 1 : 0;
    }
    #pragma unroll
    for (int u = 0; u < 4; ++u)
        if (myrank[u] < 16) { winv[wv][g][myrank[u]] = myval[u]; winf[wv][g][myrank[u]] = myflat[u]; }
    __syncthreads();

    // ---------- phase 3: h[r] = x[n] . down[flat_r], lane owns 32-dim slice
    float xr[32];
    const float* xp = x + (size_t)n * NDIM + lam * 32;
    #pragma unroll
    for (int c = 0; c < 8; ++c) {
        float4 t = *reinterpret_cast<const float4*>(xp + c * 4);
        xr[c * 4 + 0] = t.x; xr[c * 4 + 1] = t.y; xr[c * 4 + 2] = t.z; xr[c * 4 + 3] = t.w;
    }
    float hv[16];
    #pragma unroll
    for (int r = 0; r < 16; ++r) {
        const int row = winf[wv][g][r];
        const float* dp = down + (size_t)row * NDIM + lam * 32;
        float a = 0.f;
        #pragma unroll
        for (int c = 0; c < 8; ++c) {
            float4 t = *reinterpret_cast<const float4*>(dp + c * 4);
            a += xr[c * 4 + 0] * t.x + xr[c * 4 + 1] * t.y + xr[c * 4 + 2] * t.z + xr[c * 4 + 3] * t.w;
        }
        #pragma unroll
        for (int off = 1; off < 16; off <<= 1) a += __shfl_xor(a, off);
        hv[r] = a;
    }

    // ---------- phase 4: softmax(scores) * gelu(h) -> (idx, weight), one r per lane
    const float m0 = winv[wv][g][0];
    float esum = 0.f;
    #pragma unroll
    for (int r = 0; r < 16; ++r) esum += expf(winv[wv][g][r] - m0);
    const float myw = expf(winv[wv][g][lam] - m0) / esum;
    float hsel = hv[0];
    #pragma unroll
    for (int r = 1; r < 16; ++r) if (lam == r) hsel = hv[r];
    const float gg = 0.5f * hsel * (1.0f + erff(hsel * 0.70710678118654752f));
    idx_out[(size_t)pair * 16 + lam] = winf[wv][g][lam];
    w_out[(size_t)pair * 16 + lam] = myw * gg;
}

// ---------------- K4: out[n,:] = sum_{h,k} w * up_embed[idx]  (256 hot rows, L2-resident)
__global__ __launch_bounds__(256) void k4_out(const int* __restrict__ idx,
                                              const float* __restrict__ w,
                                              const float* __restrict__ up,
                                              float* __restrict__ out) {
    __shared__ int sidx[128];
    __shared__ float sw[128];
    const int n = blockIdx.x;
    const int tid = threadIdx.x;
    if (tid < 128) {
        sidx[tid] = idx[(size_t)n * 128 + tid];
        sw[tid] = w[(size_t)n * 128 + tid];
    }
    __syncthreads();
    const int d = tid * 2;
    float2 acc = {0.f, 0.f};
    for (int i = 0; i < 128; ++i) {
        float2 u = *reinterpret_cast<const float2*>(&up[(size_t)sidx[i] * NDIM + d]);
        acc.x += sw[i] * u.x;
        acc.y += sw[i] * u.y;
    }
    *reinterpret_cast<float2*>(&out[(size_t)n * NDIM + d]) = acc;
}

extern "C" void kernel_launch(void* const* d_in, const int* in_sizes, int n_in,
                              void* d_out, int out_size, void* d_ws, size_t ws_size,
                              hipStream_t stream) {
    const float* x    = (const float*)d_in[0];
    const float* Wq   = (const float*)d_in[1];
    const float* keys = (const float*)d_in[2];
    const float* down = (const float*)d_in[3];
    const float* up   = (const float*)d_in[4];
    float* out = (float*)d_out;

    char* ws = (char*)d_ws;
    float* M   = (float*)(ws);                                  //  8 MB: [512,4096]
    float* sim = (float*)(ws + (size_t)8 * 1024 * 1024);        // 32 MB: [2048,4096]
    int*   idx = (int*)  (ws + (size_t)40 * 1024 * 1024);       //  2 MB
    float* wgt = (float*)(ws + (size_t)42 * 1024 * 1024);       //  2 MB

    k1_combine<<<dim3(8, 4, 16), 256, 0, stream>>>(Wq, keys, M);
    k2_gemm<<<dim3(16, 32), 256, 0, stream>>>(x, M, sim);
    k3_topk<<<1024, 256, 0, stream>>>(sim, x, down, idx, wgt);
    k4_out<<<2048, 256, 0, stream>>>(idx, wgt, up, out);
}

// Round 3
// 208.882 us; speedup vs baseline: 1.7187x; 1.7187x over previous
//
#include <hip/hip_runtime.h>
#include <math.h>

#define N_TOK 2048
#define NDIM 512
#define HEADS 8
#define NUM_KEYS 256
#define DIM_KEY 256
#define TOPK 16
#define QCOLS 4096   // similarity columns
#define MCOLS 4352   // 4096 sim cols + 256 D cols (down256^T appended)

// ---------------- K1: M[c, p*2048+h*256+k] = sum_d Wq[c, p*2048+h*256+d] * keys[h,k,p,d]
__global__ __launch_bounds__(256) void k1_combine(const float* __restrict__ Wq,
                                                  const float* __restrict__ keys,
                                                  float* __restrict__ M) {
    __shared__ float As[16][64];
    __shared__ float Bs[16][64];
    const int ph = blockIdx.z;       // p*8 + h
    const int p = ph >> 3, h = ph & 7;
    const int off = p * 2048 + h * 256;
    const int c0 = blockIdx.x * 64;
    const int k0 = blockIdx.y * 64;
    const int tid = threadIdx.x;
    const int lr = tid >> 2;
    const int ld4 = (tid & 3) * 4;
    const int tr = tid >> 4, tc = tid & 15;
    float acc[4][4] = {};
    for (int d0 = 0; d0 < DIM_KEY; d0 += 16) {
        float4 av = *reinterpret_cast<const float4*>(&Wq[(size_t)(c0 + lr) * QCOLS + off + d0 + ld4]);
        float4 bv = *reinterpret_cast<const float4*>(&keys[(size_t)((h * 256 + (k0 + lr)) * 2 + p) * 256 + d0 + ld4]);
        __syncthreads();
        As[ld4 + 0][lr] = av.x; As[ld4 + 1][lr] = av.y; As[ld4 + 2][lr] = av.z; As[ld4 + 3][lr] = av.w;
        Bs[ld4 + 0][lr] = bv.x; Bs[ld4 + 1][lr] = bv.y; Bs[ld4 + 2][lr] = bv.z; Bs[ld4 + 3][lr] = bv.w;
        __syncthreads();
        #pragma unroll
        for (int kk = 0; kk < 16; ++kk) {
            float4 a = *reinterpret_cast<const float4*>(&As[kk][tr * 4]);
            float4 b = *reinterpret_cast<const float4*>(&Bs[kk][tc * 4]);
            float aa[4] = {a.x, a.y, a.z, a.w}, bb[4] = {b.x, b.y, b.z, b.w};
            #pragma unroll
            for (int i = 0; i < 4; ++i)
                #pragma unroll
                for (int j = 0; j < 4; ++j) acc[i][j] += aa[i] * bb[j];
        }
    }
    #pragma unroll
    for (int i = 0; i < 4; ++i) {
        float4 o = {acc[i][0], acc[i][1], acc[i][2], acc[i][3]};
        *reinterpret_cast<float4*>(&M[(size_t)(c0 + tr * 4 + i) * MCOLS + off + k0 + tc * 4]) = o;
    }
}

// ---------------- KT: append down256^T into M's last 256 columns: M[d,4096+e] = down[e,d]
__global__ __launch_bounds__(256) void kT_fill(const float* __restrict__ down,
                                               float* __restrict__ M) {
    const int d = blockIdx.x;        // 0..511
    const int e = threadIdx.x;       // 0..255
    M[(size_t)d * MCOLS + QCOLS + e] = down[(size_t)e * NDIM + d];
}

// ---------------- K2: sim_ext[2048,4352] = x[2048,512] @ M[512,4352], fp32 VALU GEMM
__global__ __launch_bounds__(256) void k2_gemm(const float* __restrict__ A,
                                               const float* __restrict__ B,
                                               float* __restrict__ C) {
    __shared__ float As[8][128];
    __shared__ float Bs[8][128];
    const int row0 = blockIdx.x * 128;
    const int col0 = blockIdx.y * 128;
    const int tid = threadIdx.x;
    const int ar = tid >> 1, ak = (tid & 1) * 4;
    const int bk = tid >> 5, bc = (tid & 31) * 4;
    const int tr = tid >> 4, tc = tid & 15;
    float acc[8][8] = {};
    for (int k0 = 0; k0 < NDIM; k0 += 8) {
        float4 av = *reinterpret_cast<const float4*>(&A[(size_t)(row0 + ar) * NDIM + k0 + ak]);
        float4 bv = *reinterpret_cast<const float4*>(&B[(size_t)(k0 + bk) * MCOLS + col0 + bc]);
        __syncthreads();
        As[ak + 0][ar] = av.x; As[ak + 1][ar] = av.y; As[ak + 2][ar] = av.z; As[ak + 3][ar] = av.w;
        *reinterpret_cast<float4*>(&Bs[bk][bc]) = bv;
        __syncthreads();
        #pragma unroll
        for (int kk = 0; kk < 8; ++kk) {
            float a[8], b[8];
            *(float4*)&a[0] = *(const float4*)&As[kk][tr * 8];
            *(float4*)&a[4] = *(const float4*)&As[kk][tr * 8 + 4];
            *(float4*)&b[0] = *(const float4*)&Bs[kk][tc * 8];
            *(float4*)&b[4] = *(const float4*)&Bs[kk][tc * 8 + 4];
            #pragma unroll
            for (int i = 0; i < 8; ++i)
                #pragma unroll
                for (int j = 0; j < 8; ++j) acc[i][j] += a[i] * b[j];
        }
    }
    #pragma unroll
    for (int i = 0; i < 8; ++i) {
        float* cp = &C[(size_t)(row0 + tr * 8 + i) * MCOLS + col0 + tc * 8];
        float4 o0 = {acc[i][0], acc[i][1], acc[i][2], acc[i][3]};
        float4 o1 = {acc[i][4], acc[i][5], acc[i][6], acc[i][7]};
        *(float4*)cp = o0;
        *(float4*)(cp + 4) = o1;
    }
}

// ---------------- K3: selection via sorting networks; outputs dense W[2048,256]
// candidate slots: 50 real cells (i+1)(j+1)<=16, 2 per lane over 32 lanes, pads 0xFF
__device__ const unsigned short CAND_TBL[32] = {
    0x0100, 0x0302, 0x0504, 0x0706, 0x0908, 0x0B0A, 0x0D0C, 0x0F0E,
    0x1110, 0x1312, 0x1514, 0x1716,
    0x2120, 0x2322, 0x3024, 0x3231, 0x4033, 0x4241,
    0x5150, 0x6160, 0x7170,
    0x9080, 0xB0A0, 0xD0C0, 0xF0E0,
    0xFFFF, 0xFFFF, 0xFFFF, 0xFFFF, 0xFFFF, 0xFFFF, 0xFFFF
};

__device__ __forceinline__ float sel16(const float a[16], int i) {
    float b0 = (i & 1) ? a[1] : a[0];
    float b1 = (i & 1) ? a[3] : a[2];
    float b2 = (i & 1) ? a[5] : a[4];
    float b3 = (i & 1) ? a[7] : a[6];
    float b4 = (i & 1) ? a[9] : a[8];
    float b5 = (i & 1) ? a[11] : a[10];
    float b6 = (i & 1) ? a[13] : a[12];
    float b7 = (i & 1) ? a[15] : a[14];
    float c0 = (i & 2) ? b1 : b0;
    float c1 = (i & 2) ? b3 : b2;
    float c2 = (i & 2) ? b5 : b4;
    float c3 = (i & 2) ? b7 : b6;
    float d0 = (i & 4) ? c1 : c0;
    float d1 = (i & 4) ? c3 : c2;
    return (i & 8) ? d1 : d0;
}

__global__ __launch_bounds__(256) void k3_sel(const float* __restrict__ sim,
                                              float* __restrict__ W) {
    __shared__ unsigned long long ckey[8][50];
    __shared__ float winval[8][16];
    __shared__ int winflat[8][16];
    __shared__ int Wrow[256];

    const int tid = threadIdx.x;
    const int n = blockIdx.x;
    const int h = tid >> 5;          // cluster = head
    const int p = (tid >> 4) & 1;    // 16-lane group within cluster
    const int lam = tid & 15;

    Wrow[tid] = 0;

    // ---- load this group's 16 values of sim[n, p, h, :]
    const float* s = sim + (size_t)n * MCOLS + p * 2048 + h * 256 + lam * 16;
    float v[16];
    #pragma unroll
    for (int c = 0; c < 4; ++c) {
        float4 t = *reinterpret_cast<const float4*>(s + c * 4);
        v[c * 4 + 0] = t.x; v[c * 4 + 1] = t.y; v[c * 4 + 2] = t.z; v[c * 4 + 3] = t.w;
    }

    // ---- in-lane bitonic sort, ascending (80 static CEs)
    #pragma unroll
    for (int k = 2; k <= 16; k <<= 1)
        #pragma unroll
        for (int j = k >> 1; j > 0; j >>= 1)
            #pragma unroll
            for (int i = 0; i < 16; ++i) {
                const int l = i ^ j;
                if (l > i) {
                    const bool asc = ((i & k) == 0);
                    const float lo = fminf(v[i], v[l]), hi = fmaxf(v[i], v[l]);
                    v[i] = asc ? lo : hi;
                    v[l] = asc ? hi : lo;
                }
            }

    // ---- 4 cross-lane merge levels: keep top-16 multiset, re-sort (bitonic merge)
    #pragma unroll
    for (int lvl = 1; lvl <= 8; lvl <<= 1) {
        float m[16];
        #pragma unroll
        for (int q = 0; q < 16; ++q)
            m[q] = fmaxf(v[q], __shfl_xor(v[15 - q], lvl));
        #pragma unroll
        for (int j = 8; j > 0; j >>= 1)
            #pragma unroll
            for (int i = 0; i < 16; ++i) {
                const int l = i ^ j;
                if (l > i) {
                    const float lo = fminf(m[i], m[l]), hi = fmaxf(m[i], m[l]);
                    m[i] = lo; m[l] = hi;
                }
            }
        #pragma unroll
        for (int q = 0; q < 16; ++q) v[q] = m[q];
    }
    // every lane of the 16-group now holds the group's sorted top-16 (ascending)

    // ---- exchange across p halves; build descending sx, sy in-register
    float other[16];
    #pragma unroll
    for (int q = 0; q < 16; ++q) other[q] = __shfl_xor(v[q], 16);
    const bool isP1 = (tid & 16) != 0;
    float sxd[16], syd[16];
    #pragma unroll
    for (int q = 0; q < 16; ++q) {
        const float own = v[15 - q], oth = other[15 - q];
        sxd[q] = isP1 ? oth : own;
        syd[q] = isP1 ? own : oth;
    }

    // ---- 50 monotone-matrix candidates, keys (val desc, flat asc)
    const int lc = tid & 31;
    const unsigned int cw = CAND_TBL[lc];
    unsigned long long mykey[2]; float myval[2]; int myflat[2]; int myrank[2] = {0, 0};
    #pragma unroll
    for (int u = 0; u < 2; ++u) {
        const int fl = (cw >> (8 * u)) & 0xFF;   // fl == (i<<4)|j == flat index
        const float sv = sel16(sxd, fl >> 4) + sel16(syd, fl & 15);
        const unsigned int uv = __float_as_uint(sv);
        const unsigned int mo = (uv & 0x80000000u) ? ~uv : (uv | 0x80000000u);
        mykey[u] = ((unsigned long long)mo << 8) | (unsigned long long)(255 - fl);
        myval[u] = sv; myflat[u] = fl;
        const int slot = lc * 2 + u;
        if (slot < 50) ckey[h][slot] = mykey[u];
    }
    __syncthreads();
    for (int kk = 0; kk < 50; ++kk) {
        const unsigned long long ok = ckey[h][kk];
        myrank[0] += (ok > mykey[0]) ? 1 : 0;
        myrank[1] += (ok > mykey[1]) ? 1 : 0;
    }
    #pragma unroll
    for (int u = 0; u < 2; ++u)
        if (myrank[u] < 16) { winval[h][myrank[u]] = myval[u]; winflat[h][myrank[u]] = myflat[u]; }
    __syncthreads();

    // ---- softmax * gelu(D[n,flat]) -> fixed-point scatter into Wrow
    if (!(tid & 16)) {
        const float sc = winval[h][lam];
        const float m0 = winval[h][0];
        float e = expf(sc - m0);
        float esum = e;
        #pragma unroll
        for (int off = 1; off < 16; off <<= 1) esum += __shfl_xor(esum, off);
        const int fl = winflat[h][lam];
        const float hv = sim[(size_t)n * MCOLS + QCOLS + fl];
        const float g = 0.5f * hv * (1.0f + erff(hv * 0.70710678118654752f));
        const float w = (e / esum) * g;
        atomicAdd(&Wrow[fl], __float2int_rn(w * 4194304.0f));   // 2^22 fixed point
    }
    __syncthreads();
    W[(size_t)n * 256 + tid] = (float)Wrow[tid] * (1.0f / 4194304.0f);
}

// ---------------- K5: out[2048,512] = W[2048,256] @ up[0:256,512]
__global__ __launch_bounds__(256) void k5_out(const float* __restrict__ W,
                                              const float* __restrict__ up,
                                              float* __restrict__ out) {
    __shared__ float As[16][64];
    __shared__ float Bs[16][64];
    const int row0 = blockIdx.x * 64;
    const int col0 = blockIdx.y * 64;
    const int tid = threadIdx.x;
    const int ar = tid >> 2, ak = (tid & 3) * 4;
    const int bk = tid >> 4, bc = (tid & 15) * 4;
    const int tr = tid >> 4, tc = tid & 15;
    float acc[4][4] = {};
    for (int k0 = 0; k0 < 256; k0 += 16) {
        float4 av = *reinterpret_cast<const float4*>(&W[(size_t)(row0 + ar) * 256 + k0 + ak]);
        float4 bv = *reinterpret_cast<const float4*>(&up[(size_t)(k0 + bk) * NDIM + col0 + bc]);
        __syncthreads();
        As[ak + 0][ar] = av.x; As[ak + 1][ar] = av.y; As[ak + 2][ar] = av.z; As[ak + 3][ar] = av.w;
        *reinterpret_cast<float4*>(&Bs[bk][bc]) = bv;
        __syncthreads();
        #pragma unroll
        for (int kk = 0; kk < 16; ++kk) {
            float4 a = *(const float4*)&As[kk][tr * 4];
            float4 b = *(const float4*)&Bs[kk][tc * 4];
            float aa[4] = {a.x, a.y, a.z, a.w}, bb[4] = {b.x, b.y, b.z, b.w};
            #pragma unroll
            for (int i = 0; i < 4; ++i)
                #pragma unroll
                for (int j = 0; j < 4; ++j) acc[i][j] += aa[i] * bb[j];
        }
    }
    #pragma unroll
    for (int i = 0; i < 4; ++i) {
        float4 o = {acc[i][0], acc[i][1], acc[i][2], acc[i][3]};
        *reinterpret_cast<float4*>(&out[(size_t)(row0 + tr * 4 + i) * NDIM + col0 + tc * 4]) = o;
    }
}

extern "C" void kernel_launch(void* const* d_in, const int* in_sizes, int n_in,
                              void* d_out, int out_size, void* d_ws, size_t ws_size,
                              hipStream_t stream) {
    const float* x    = (const float*)d_in[0];
    const float* Wq   = (const float*)d_in[1];
    const float* keys = (const float*)d_in[2];
    const float* down = (const float*)d_in[3];
    const float* up   = (const float*)d_in[4];
    float* out = (float*)d_out;

    char* ws = (char*)d_ws;
    float* M   = (float*)(ws);                         // 512*4352*4  = 8.9 MB
    float* sim = (float*)(ws + (size_t)9437184);       // 2048*4352*4 = 35.7 MB
    float* W   = (float*)(ws + (size_t)45088768);      // 2048*256*4  = 2 MB

    kT_fill<<<512, 256, 0, stream>>>(down, M);
    k1_combine<<<dim3(8, 4, 16), 256, 0, stream>>>(Wq, keys, M);
    k2_gemm<<<dim3(16, 34), 256, 0, stream>>>(x, M, sim);
    k3_sel<<<2048, 256, 0, stream>>>(sim, W);
    k5_out<<<dim3(32, 8), 256, 0, stream>>>(W, up, out);
}

// Round 4
// 125.413 us; speedup vs baseline: 2.8626x; 1.6656x over previous
//
#include <hip/hip_runtime.h>
#include <math.h>

#define N_TOK 2048
#define NDIM 512
#define HEADS 8
#define TOPK 16
#define QCOLS 4096   // similarity columns
#define MCOLS 4352   // 4096 sim cols + 256 D cols (x . down256 appended)

typedef __attribute__((ext_vector_type(8))) short bf16x8;
typedef __attribute__((ext_vector_type(4))) float f32x4;

__device__ __forceinline__ unsigned short f32_to_bf16(float f) {
    unsigned u = __float_as_uint(f);
    u += 0x7FFFu + ((u >> 16) & 1u);   // round-to-nearest-even
    return (unsigned short)(u >> 16);
}
__device__ __forceinline__ float bf16_to_f32(unsigned short h) {
    return __uint_as_float(((unsigned)h) << 16);
}
__device__ __forceinline__ void gl_lds16(const void* g, void* l) {
    __builtin_amdgcn_global_load_lds(
        (const __attribute__((address_space(1))) void*)g,
        (__attribute__((address_space(3))) void*)l, 16, 0, 0);
}

// ---------------- KX: split x (fp32) -> xh + xl (bf16 pair)
__global__ __launch_bounds__(256) void kX_split(const float* __restrict__ x,
                                                unsigned short* __restrict__ xh,
                                                unsigned short* __restrict__ xl) {
    const int i = blockIdx.x * 256 + threadIdx.x;    // one float4 each
    float4 v = reinterpret_cast<const float4*>(x)[i];
    float vv[4] = {v.x, v.y, v.z, v.w};
    ushort4 h, lo;
    unsigned short* hp = &h.x; unsigned short* lp = &lo.x;
    #pragma unroll
    for (int t = 0; t < 4; ++t) {
        unsigned short hh = f32_to_bf16(vv[t]);
        hp[t] = hh;
        lp[t] = f32_to_bf16(vv[t] - bf16_to_f32(hh));
    }
    reinterpret_cast<ushort4*>(xh)[i] = h;
    reinterpret_cast<ushort4*>(xl)[i] = lo;
}

// ---------------- KT: Mt rows 4096..4351 = bf16 split of down_embed rows 0..255
__global__ __launch_bounds__(256) void kT_fill(const float* __restrict__ down,
                                               unsigned short* __restrict__ Mth,
                                               unsigned short* __restrict__ Mtl) {
    const int e = blockIdx.x;        // 0..255
    const int d0 = threadIdx.x * 2;  // 0..510
    float2 v = *reinterpret_cast<const float2*>(&down[(size_t)e * NDIM + d0]);
    ushort2 h, lo;
    unsigned short h0 = f32_to_bf16(v.x);
    unsigned short h1 = f32_to_bf16(v.y);
    h.x = h0; h.y = h1;
    lo.x = f32_to_bf16(v.x - bf16_to_f32(h0));
    lo.y = f32_to_bf16(v.y - bf16_to_f32(h1));
    *reinterpret_cast<ushort2*>(&Mth[(size_t)(QCOLS + e) * NDIM + d0]) = h;
    *reinterpret_cast<ushort2*>(&Mtl[(size_t)(QCOLS + e) * NDIM + d0]) = lo;
}

// ---------------- K1: M[c, col] = sum_d Wq[c, off+d] * keys[h,k,p,d], written
// TRANSPOSED as bf16 hi/lo: Mth/Mtl[col][c]
__global__ __launch_bounds__(256) void k1_combine(const float* __restrict__ Wq,
                                                  const float* __restrict__ keys,
                                                  unsigned short* __restrict__ Mth,
                                                  unsigned short* __restrict__ Mtl) {
    __shared__ float As[16][64];
    __shared__ float Bs[16][64];
    const int ph = blockIdx.z;       // p*8 + h
    const int p = ph >> 3, h = ph & 7;
    const int off = p * 2048 + h * 256;
    const int c0 = blockIdx.x * 64;
    const int k0 = blockIdx.y * 64;
    const int tid = threadIdx.x;
    const int lr = tid >> 2;
    const int ld4 = (tid & 3) * 4;
    const int tr = tid >> 4, tc = tid & 15;
    float acc[4][4] = {};
    for (int d0 = 0; d0 < 256; d0 += 16) {
        float4 av = *reinterpret_cast<const float4*>(&Wq[(size_t)(c0 + lr) * QCOLS + off + d0 + ld4]);
        float4 bv = *reinterpret_cast<const float4*>(&keys[(size_t)((h * 256 + (k0 + lr)) * 2 + p) * 256 + d0 + ld4]);
        __syncthreads();
        As[ld4 + 0][lr] = av.x; As[ld4 + 1][lr] = av.y; As[ld4 + 2][lr] = av.z; As[ld4 + 3][lr] = av.w;
        Bs[ld4 + 0][lr] = bv.x; Bs[ld4 + 1][lr] = bv.y; Bs[ld4 + 2][lr] = bv.z; Bs[ld4 + 3][lr] = bv.w;
        __syncthreads();
        #pragma unroll
        for (int kk = 0; kk < 16; ++kk) {
            float4 a = *reinterpret_cast<const float4*>(&As[kk][tr * 4]);
            float4 b = *reinterpret_cast<const float4*>(&Bs[kk][tc * 4]);
            float aa[4] = {a.x, a.y, a.z, a.w}, bb[4] = {b.x, b.y, b.z, b.w};
            #pragma unroll
            for (int i = 0; i < 4; ++i)
                #pragma unroll
                for (int j = 0; j < 4; ++j) acc[i][j] += aa[i] * bb[j];
        }
    }
    #pragma unroll
    for (int j = 0; j < 4; ++j) {
        const int col = off + k0 + tc * 4 + j;
        ushort4 h4, l4;
        unsigned short* hp = &h4.x; unsigned short* lp = &l4.x;
        #pragma unroll
        for (int i = 0; i < 4; ++i) {
            float v = acc[i][j];
            unsigned short hh = f32_to_bf16(v);
            hp[i] = hh;
            lp[i] = f32_to_bf16(v - bf16_to_f32(hh));
        }
        *reinterpret_cast<ushort4*>(&Mth[(size_t)col * NDIM + c0 + tr * 4]) = h4;
        *reinterpret_cast<ushort4*>(&Mtl[(size_t)col * NDIM + c0 + tr * 4]) = l4;
    }
}

// ---------------- K2: sim[2048,4352] = x @ M via 3-pass split-bf16 MFMA
// C = xh*Mh + xh*Ml + xl*Mh. Tiles 64x128, BK=64, 4 waves (2x2), m97-style.
#define BM 64
#define BN 128
#define BK 64
__global__ __launch_bounds__(256) void k2_mfma(const unsigned short* __restrict__ xh,
                                               const unsigned short* __restrict__ xl,
                                               const unsigned short* __restrict__ Mth,
                                               const unsigned short* __restrict__ Mtl,
                                               float* __restrict__ C) {
    __shared__ __align__(16) unsigned short ldsA[BM * BK];   //  8 KB
    __shared__ __align__(16) unsigned short ldsB[BN * BK];   // 16 KB
    const int tid = threadIdx.x;
    const int w = tid >> 6, l = tid & 63;
    const int row0 = blockIdx.x * BM;
    const int col0 = blockIdx.y * BN;
    const int wm = w >> 1, wn = w & 1;     // wave tile: 32 x 64
    f32x4 acc[2][4] = {};

    for (int s = 0; s < 24; ++s) {
        const int pass = s >> 3;
        const int kk = (s & 7) * BK;
        const unsigned short* Ab = (pass == 2) ? xl : xh;
        const unsigned short* Bb = (pass == 1) ? Mtl : Mth;
        __syncthreads();   // prior compute done before LDS overwrite
        // stage A (8 KB): linear LDS dest, inverse-swizzled global source
        #pragma unroll
        for (int t = 0; t < 2; ++t) {
            const int qq = w * 2048 + t * 1024 + l * 16;     // dest byte (this lane)
            const int row = qq >> 7;                          // /128B per row
            const int bs = (qq & 127) ^ ((row & 7) << 4);     // source byte in row
            gl_lds16(Ab + (size_t)(row0 + row) * NDIM + kk + (bs >> 1),
                     (char*)ldsA + w * 2048 + t * 1024);
        }
        // stage B (16 KB)
        #pragma unroll
        for (int t = 0; t < 4; ++t) {
            const int qq = w * 4096 + t * 1024 + l * 16;
            const int row = qq >> 7;
            const int bs = (qq & 127) ^ ((row & 7) << 4);
            gl_lds16(Bb + (size_t)(col0 + row) * NDIM + kk + (bs >> 1),
                     (char*)ldsB + w * 4096 + t * 1024);
        }
        __syncthreads();   // vmcnt drained by compiler before barrier
        #pragma unroll
        for (int kc = 0; kc < 2; ++kc) {
            bf16x8 af[2], bfr[4];
            #pragma unroll
            for (int mi = 0; mi < 2; ++mi) {
                const int row = wm * 32 + mi * 16 + (l & 15);
                const int b = (kc * 64 + (l >> 4) * 16) ^ ((row & 7) << 4);
                af[mi] = *(const bf16x8*)((const char*)ldsA + row * 128 + b);
            }
            #pragma unroll
            for (int nj = 0; nj < 4; ++nj) {
                const int row = wn * 64 + nj * 16 + (l & 15);
                const int b = (kc * 64 + (l >> 4) * 16) ^ ((row & 7) << 4);
                bfr[nj] = *(const bf16x8*)((const char*)ldsB + row * 128 + b);
            }
            #pragma unroll
            for (int mi = 0; mi < 2; ++mi)
                #pragma unroll
                for (int nj = 0; nj < 4; ++nj)
                    acc[mi][nj] = __builtin_amdgcn_mfma_f32_16x16x32_bf16(
                        af[mi], bfr[nj], acc[mi][nj], 0, 0, 0);
        }
    }
    #pragma unroll
    for (int mi = 0; mi < 2; ++mi)
        #pragma unroll
        for (int nj = 0; nj < 4; ++nj)
            #pragma unroll
            for (int r = 0; r < 4; ++r) {
                const int row = row0 + wm * 32 + mi * 16 + (l >> 4) * 4 + r;
                const int col = col0 + wn * 64 + nj * 16 + (l & 15);
                C[(size_t)row * MCOLS + col] = acc[mi][nj][r];
            }
}

// ---------------- K3: selection via sorting networks; outputs dense W[2048,256]
__device__ const unsigned short CAND_TBL[32] = {
    0x0100, 0x0302, 0x0504, 0x0706, 0x0908, 0x0B0A, 0x0D0C, 0x0F0E,
    0x1110, 0x1312, 0x1514, 0x1716,
    0x2120, 0x2322, 0x3024, 0x3231, 0x4033, 0x4241,
    0x5150, 0x6160, 0x7170,
    0x9080, 0xB0A0, 0xD0C0, 0xF0E0,
    0xFFFF, 0xFFFF, 0xFFFF, 0xFFFF, 0xFFFF, 0xFFFF, 0xFFFF
};

__device__ __forceinline__ float sel16(const float a[16], int i) {
    float b0 = (i & 1) ? a[1] : a[0];
    float b1 = (i & 1) ? a[3] : a[2];
    float b2 = (i & 1) ? a[5] : a[4];
    float b3 = (i & 1) ? a[7] : a[6];
    float b4 = (i & 1) ? a[9] : a[8];
    float b5 = (i & 1) ? a[11] : a[10];
    float b6 = (i & 1) ? a[13] : a[12];
    float b7 = (i & 1) ? a[15] : a[14];
    float c0 = (i & 2) ? b1 : b0;
    float c1 = (i & 2) ? b3 : b2;
    float c2 = (i & 2) ? b5 : b4;
    float c3 = (i & 2) ? b7 : b6;
    float d0 = (i & 4) ? c1 : c0;
    float d1 = (i & 4) ? c3 : c2;
    return (i & 8) ? d1 : d0;
}

__global__ __launch_bounds__(256) void k3_sel(const float* __restrict__ sim,
                                              float* __restrict__ W) {
    __shared__ unsigned long long ckey[8][50];
    __shared__ float winval[8][16];
    __shared__ int winflat[8][16];
    __shared__ int Wrow[256];

    const int tid = threadIdx.x;
    const int n = blockIdx.x;
    const int h = tid >> 5;
    const int p = (tid >> 4) & 1;
    const int lam = tid & 15;

    Wrow[tid] = 0;

    const float* s = sim + (size_t)n * MCOLS + p * 2048 + h * 256 + lam * 16;
    float v[16];
    #pragma unroll
    for (int c = 0; c < 4; ++c) {
        float4 t = *reinterpret_cast<const float4*>(s + c * 4);
        v[c * 4 + 0] = t.x; v[c * 4 + 1] = t.y; v[c * 4 + 2] = t.z; v[c * 4 + 3] = t.w;
    }

    #pragma unroll
    for (int k = 2; k <= 16; k <<= 1)
        #pragma unroll
        for (int j = k >> 1; j > 0; j >>= 1)
            #pragma unroll
            for (int i = 0; i < 16; ++i) {
                const int l2 = i ^ j;
                if (l2 > i) {
                    const bool asc = ((i & k) == 0);
                    const float lo = fminf(v[i], v[l2]), hi = fmaxf(v[i], v[l2]);
                    v[i] = asc ? lo : hi;
                    v[l2] = asc ? hi : lo;
                }
            }

    #pragma unroll
    for (int lvl = 1; lvl <= 8; lvl <<= 1) {
        float m[16];
        #pragma unroll
        for (int q = 0; q < 16; ++q)
            m[q] = fmaxf(v[q], __shfl_xor(v[15 - q], lvl));
        #pragma unroll
        for (int j = 8; j > 0; j >>= 1)
            #pragma unroll
            for (int i = 0; i < 16; ++i) {
                const int l2 = i ^ j;
                if (l2 > i) {
                    const float lo = fminf(m[i], m[l2]), hi = fmaxf(m[i], m[l2]);
                    m[i] = lo; m[l2] = hi;
                }
            }
        #pragma unroll
        for (int q = 0; q < 16; ++q) v[q] = m[q];
    }

    float other[16];
    #pragma unroll
    for (int q = 0; q < 16; ++q) other[q] = __shfl_xor(v[q], 16);
    const bool isP1 = (tid & 16) != 0;
    float sxd[16], syd[16];
    #pragma unroll
    for (int q = 0; q < 16; ++q) {
        const float own = v[15 - q], oth = other[15 - q];
        sxd[q] = isP1 ? oth : own;
        syd[q] = isP1 ? own : oth;
    }

    const int lc = tid & 31;
    const unsigned int cw = CAND_TBL[lc];
    unsigned long long mykey[2]; float myval[2]; int myflat[2]; int myrank[2] = {0, 0};
    #pragma unroll
    for (int u = 0; u < 2; ++u) {
        const int fl = (cw >> (8 * u)) & 0xFF;
        const float sv = sel16(sxd, fl >> 4) + sel16(syd, fl & 15);
        const unsigned int uv = __float_as_uint(sv);
        const unsigned int mo = (uv & 0x80000000u) ? ~uv : (uv | 0x80000000u);
        mykey[u] = ((unsigned long long)mo << 8) | (unsigned long long)(255 - fl);
        myval[u] = sv; myflat[u] = fl;
        const int slot = lc * 2 + u;
        if (slot < 50) ckey[h][slot] = mykey[u];
    }
    __syncthreads();
    for (int kk = 0; kk < 50; ++kk) {
        const unsigned long long ok = ckey[h][kk];
        myrank[0] += (ok > mykey[0]) ? 1 : 0;
        myrank[1] += (ok > mykey[1]) ? 1 : 0;
    }
    #pragma unroll
    for (int u = 0; u < 2; ++u)
        if (myrank[u] < 16) { winval[h][myrank[u]] = myval[u]; winflat[h][myrank[u]] = myflat[u]; }
    __syncthreads();

    if (!(tid & 16)) {
        const float sc = winval[h][lam];
        const float m0 = winval[h][0];
        float e = expf(sc - m0);
        float esum = e;
        #pragma unroll
        for (int off = 1; off < 16; off <<= 1) esum += __shfl_xor(esum, off);
        const int fl = winflat[h][lam];
        const float hv = sim[(size_t)n * MCOLS + QCOLS + fl];
        const float g = 0.5f * hv * (1.0f + erff(hv * 0.70710678118654752f));
        const float w = (e / esum) * g;
        atomicAdd(&Wrow[fl], __float2int_rn(w * 4194304.0f));
    }
    __syncthreads();
    W[(size_t)n * 256 + tid] = (float)Wrow[tid] * (1.0f / 4194304.0f);
}

// ---------------- K5: out[2048,512] = W[2048,256] @ up[0:256,512]
__global__ __launch_bounds__(256) void k5_out(const float* __restrict__ W,
                                              const float* __restrict__ up,
                                              float* __restrict__ out) {
    __shared__ float As[16][64];
    __shared__ float Bs[16][64];
    const int row0 = blockIdx.x * 64;
    const int col0 = blockIdx.y * 64;
    const int tid = threadIdx.x;
    const int ar = tid >> 2, ak = (tid & 3) * 4;
    const int bk = tid >> 4, bc = (tid & 15) * 4;
    const int tr = tid >> 4, tc = tid & 15;
    float acc[4][4] = {};
    for (int k0 = 0; k0 < 256; k0 += 16) {
        float4 av = *reinterpret_cast<const float4*>(&W[(size_t)(row0 + ar) * 256 + k0 + ak]);
        float4 bv = *reinterpret_cast<const float4*>(&up[(size_t)(k0 + bk) * NDIM + col0 + bc]);
        __syncthreads();
        As[ak + 0][ar] = av.x; As[ak + 1][ar] = av.y; As[ak + 2][ar] = av.z; As[ak + 3][ar] = av.w;
        *reinterpret_cast<float4*>(&Bs[bk][bc]) = bv;
        __syncthreads();
        #pragma unroll
        for (int kk = 0; kk < 16; ++kk) {
            float4 a = *(const float4*)&As[kk][tr * 4];
            float4 b = *(const float4*)&Bs[kk][tc * 4];
            float aa[4] = {a.x, a.y, a.z, a.w}, bb[4] = {b.x, b.y, b.z, b.w};
            #pragma unroll
            for (int i = 0; i < 4; ++i)
                #pragma unroll
                for (int j = 0; j < 4; ++j) acc[i][j] += aa[i] * bb[j];
        }
    }
    #pragma unroll
    for (int i = 0; i < 4; ++i) {
        float4 o = {acc[i][0], acc[i][1], acc[i][2], acc[i][3]};
        *reinterpret_cast<float4*>(&out[(size_t)(row0 + tr * 4 + i) * NDIM + col0 + tc * 4]) = o;
    }
}

extern "C" void kernel_launch(void* const* d_in, const int* in_sizes, int n_in,
                              void* d_out, int out_size, void* d_ws, size_t ws_size,
                              hipStream_t stream) {
    const float* x    = (const float*)d_in[0];
    const float* Wq   = (const float*)d_in[1];
    const float* keys = (const float*)d_in[2];
    const float* down = (const float*)d_in[3];
    const float* up   = (const float*)d_in[4];
    float* out = (float*)d_out;

    char* ws = (char*)d_ws;
    unsigned short* Mth = (unsigned short*)(ws);                       // 4352*512*2 = 4,456,448
    unsigned short* Mtl = (unsigned short*)(ws + 4456448);             // 4,456,448
    unsigned short* xh  = (unsigned short*)(ws + 8912896);             // 2,097,152
    unsigned short* xl  = (unsigned short*)(ws + 11010048);            // 2,097,152
    float* sim          = (float*)(ws + 13107200);                     // 35,651,584
    float* W            = (float*)(ws + 48758784);                     // 2,097,152

    kX_split<<<1024, 256, 0, stream>>>(x, xh, xl);
    kT_fill<<<256, 256, 0, stream>>>(down, Mth, Mtl);
    k1_combine<<<dim3(8, 4, 16), 256, 0, stream>>>(Wq, keys, Mth, Mtl);
    k2_mfma<<<dim3(32, 34), 256, 0, stream>>>(xh, xl, Mth, Mtl, sim);
    k3_sel<<<2048, 256, 0, stream>>>(sim, W);
    k5_out<<<dim3(32, 8), 256, 0, stream>>>(W, up, out);
}

// Round 5
// 112.719 us; speedup vs baseline: 3.1849x; 1.1126x over previous
//
#include <hip/hip_runtime.h>
#include <math.h>

#define N_TOK 2048
#define NDIM 512
#define HEADS 8
#define TOPK 16
#define QCOLS 4096   // similarity columns
#define MCOLS 4352   // 4096 sim cols + 256 D cols (x . down256 appended)

typedef __attribute__((ext_vector_type(8))) _Float16 f16x8;
typedef __attribute__((ext_vector_type(4))) float f32x4;

__device__ __forceinline__ unsigned short f32_to_f16(float f) {
    _Float16 h = (_Float16)f;
    return __builtin_bit_cast(unsigned short, h);
}
__device__ __forceinline__ float f16_to_f32(unsigned short u) {
    return (float)__builtin_bit_cast(_Float16, u);
}
__device__ __forceinline__ void gl_lds16(const void* g, void* l) {
    __builtin_amdgcn_global_load_lds(
        (const __attribute__((address_space(1))) void*)g,
        (__attribute__((address_space(3))) void*)l, 16, 0, 0);
}

// ---------------- kPrep: (a) split x -> xh+xl fp16; (b) down rows -> Mt rows 4096.. as fp16 hi/lo
__global__ __launch_bounds__(256) void kPrep(const float* __restrict__ x,
                                             const float* __restrict__ down,
                                             unsigned short* __restrict__ xh,
                                             unsigned short* __restrict__ xl,
                                             unsigned short* __restrict__ Mth,
                                             unsigned short* __restrict__ Mtl) {
    const int bid = blockIdx.x;
    const int tid = threadIdx.x;
    if (bid < 1024) {               // x split: one float4 per thread
        const int i = bid * 256 + tid;
        float4 v = reinterpret_cast<const float4*>(x)[i];
        float vv[4] = {v.x, v.y, v.z, v.w};
        ushort4 h, lo;
        unsigned short* hp = &h.x; unsigned short* lp = &lo.x;
        #pragma unroll
        for (int t = 0; t < 4; ++t) {
            unsigned short hh = f32_to_f16(vv[t]);
            hp[t] = hh;
            lp[t] = f32_to_f16(vv[t] - f16_to_f32(hh));
        }
        reinterpret_cast<ushort4*>(xh)[i] = h;
        reinterpret_cast<ushort4*>(xl)[i] = lo;
    } else {                        // down row e -> Mt row 4096+e (fp16 hi/lo)
        const int e = bid - 1024;   // 0..255
        const int d0 = tid * 2;
        float2 v = *reinterpret_cast<const float2*>(&down[(size_t)e * NDIM + d0]);
        ushort2 h, lo;
        unsigned short h0 = f32_to_f16(v.x);
        unsigned short h1 = f32_to_f16(v.y);
        h.x = h0; h.y = h1;
        lo.x = f32_to_f16(v.x - f16_to_f32(h0));
        lo.y = f32_to_f16(v.y - f16_to_f32(h1));
        *reinterpret_cast<ushort2*>(&Mth[(size_t)(QCOLS + e) * NDIM + d0]) = h;
        *reinterpret_cast<ushort2*>(&Mtl[(size_t)(QCOLS + e) * NDIM + d0]) = lo;
    }
}

// ---------------- K1: M[c, col] = sum_d Wq[c, off+d] * keys[h,k,p,d]  (fp32 VALU),
// written TRANSPOSED as fp16 hi/lo: Mth/Mtl[col][c]
__global__ __launch_bounds__(256) void k1_combine(const float* __restrict__ Wq,
                                                  const float* __restrict__ keys,
                                                  unsigned short* __restrict__ Mth,
                                                  unsigned short* __restrict__ Mtl) {
    __shared__ float As[16][64];
    __shared__ float Bs[16][64];
    const int ph = blockIdx.z;       // p*8 + h
    const int p = ph >> 3, h = ph & 7;
    const int off = p * 2048 + h * 256;
    const int c0 = blockIdx.x * 64;
    const int k0 = blockIdx.y * 64;
    const int tid = threadIdx.x;
    const int lr = tid >> 2;
    const int ld4 = (tid & 3) * 4;
    const int tr = tid >> 4, tc = tid & 15;
    float acc[4][4] = {};
    for (int d0 = 0; d0 < 256; d0 += 16) {
        float4 av = *reinterpret_cast<const float4*>(&Wq[(size_t)(c0 + lr) * QCOLS + off + d0 + ld4]);
        float4 bv = *reinterpret_cast<const float4*>(&keys[(size_t)((h * 256 + (k0 + lr)) * 2 + p) * 256 + d0 + ld4]);
        __syncthreads();
        As[ld4 + 0][lr] = av.x; As[ld4 + 1][lr] = av.y; As[ld4 + 2][lr] = av.z; As[ld4 + 3][lr] = av.w;
        Bs[ld4 + 0][lr] = bv.x; Bs[ld4 + 1][lr] = bv.y; Bs[ld4 + 2][lr] = bv.z; Bs[ld4 + 3][lr] = bv.w;
        __syncthreads();
        #pragma unroll
        for (int kk = 0; kk < 16; ++kk) {
            float4 a = *reinterpret_cast<const float4*>(&As[kk][tr * 4]);
            float4 b = *reinterpret_cast<const float4*>(&Bs[kk][tc * 4]);
            float aa[4] = {a.x, a.y, a.z, a.w}, bb[4] = {b.x, b.y, b.z, b.w};
            #pragma unroll
            for (int i = 0; i < 4; ++i)
                #pragma unroll
                for (int j = 0; j < 4; ++j) acc[i][j] += aa[i] * bb[j];
        }
    }
    #pragma unroll
    for (int j = 0; j < 4; ++j) {
        const int col = off + k0 + tc * 4 + j;
        ushort4 h4, l4;
        unsigned short* hp = &h4.x; unsigned short* lp = &l4.x;
        #pragma unroll
        for (int i = 0; i < 4; ++i) {
            float v = acc[i][j];
            unsigned short hh = f32_to_f16(v);
            hp[i] = hh;
            lp[i] = f32_to_f16(v - f16_to_f32(hh));
        }
        *reinterpret_cast<ushort4*>(&Mth[(size_t)col * NDIM + c0 + tr * 4]) = h4;
        *reinterpret_cast<ushort4*>(&Mtl[(size_t)col * NDIM + c0 + tr * 4]) = l4;
    }
}

// ---------------- K2: sim = xh*Mh + xh*Ml + xl*Mh, fp16 3-term split, fused per-kk.
// Tiles 64x128, BK=64, 8 fused K-steps, 4 waves (2x2), 48 KB LDS.
#define BM 64
#define BN 128
#define BK 64
__global__ __launch_bounds__(256, 4) void k2_mfma(const unsigned short* __restrict__ xh,
                                                  const unsigned short* __restrict__ xl,
                                                  const unsigned short* __restrict__ Mth,
                                                  const unsigned short* __restrict__ Mtl,
                                                  float* __restrict__ C) {
    __shared__ __align__(16) unsigned short ldsAh[BM * BK];   //  8 KB
    __shared__ __align__(16) unsigned short ldsAl[BM * BK];   //  8 KB
    __shared__ __align__(16) unsigned short ldsBh[BN * BK];   // 16 KB
    __shared__ __align__(16) unsigned short ldsBl[BN * BK];   // 16 KB
    const int tid = threadIdx.x;
    const int w = tid >> 6, l = tid & 63;
    const int row0 = blockIdx.x * BM;
    const int col0 = blockIdx.y * BN;
    const int wm = w >> 1, wn = w & 1;     // wave tile: 32 x 64
    f32x4 acc[2][4] = {};

    for (int s = 0; s < 8; ++s) {
        const int kk = s * BK;
        __syncthreads();   // prior compute done before LDS overwrite
        // stage A tiles (8 KB each): linear LDS dest, inverse-swizzled global source
        #pragma unroll
        for (int t = 0; t < 2; ++t) {
            const int qq = w * 2048 + t * 1024 + l * 16;      // dest byte (this lane)
            const int row = qq >> 7;
            const int bs = (qq & 127) ^ ((row & 7) << 4);
            const size_t gsrc = (size_t)(row0 + row) * NDIM + kk + (bs >> 1);
            gl_lds16(xh + gsrc, (char*)ldsAh + w * 2048 + t * 1024);
            gl_lds16(xl + gsrc, (char*)ldsAl + w * 2048 + t * 1024);
        }
        // stage B tiles (16 KB each)
        #pragma unroll
        for (int t = 0; t < 4; ++t) {
            const int qq = w * 4096 + t * 1024 + l * 16;
            const int row = qq >> 7;
            const int bs = (qq & 127) ^ ((row & 7) << 4);
            const size_t gsrc = (size_t)(col0 + row) * NDIM + kk + (bs >> 1);
            gl_lds16(Mth + gsrc, (char*)ldsBh + w * 4096 + t * 1024);
            gl_lds16(Mtl + gsrc, (char*)ldsBl + w * 4096 + t * 1024);
        }
        __syncthreads();   // compiler drains vmcnt before barrier
        #pragma unroll
        for (int kc = 0; kc < 2; ++kc) {
            f16x8 ah[2], al[2], bh[4], bl[4];
            #pragma unroll
            for (int mi = 0; mi < 2; ++mi) {
                const int row = wm * 32 + mi * 16 + (l & 15);
                const int b = (kc * 64 + (l >> 4) * 16) ^ ((row & 7) << 4);
                ah[mi] = *(const f16x8*)((const char*)ldsAh + row * 128 + b);
                al[mi] = *(const f16x8*)((const char*)ldsAl + row * 128 + b);
            }
            #pragma unroll
            for (int nj = 0; nj < 4; ++nj) {
                const int row = wn * 64 + nj * 16 + (l & 15);
                const int b = (kc * 64 + (l >> 4) * 16) ^ ((row & 7) << 4);
                bh[nj] = *(const f16x8*)((const char*)ldsBh + row * 128 + b);
                bl[nj] = *(const f16x8*)((const char*)ldsBl + row * 128 + b);
            }
            #pragma unroll
            for (int mi = 0; mi < 2; ++mi)
                #pragma unroll
                for (int nj = 0; nj < 4; ++nj) {
                    acc[mi][nj] = __builtin_amdgcn_mfma_f32_16x16x32_f16(ah[mi], bh[nj], acc[mi][nj], 0, 0, 0);
                    acc[mi][nj] = __builtin_amdgcn_mfma_f32_16x16x32_f16(ah[mi], bl[nj], acc[mi][nj], 0, 0, 0);
                    acc[mi][nj] = __builtin_amdgcn_mfma_f32_16x16x32_f16(al[mi], bh[nj], acc[mi][nj], 0, 0, 0);
                }
        }
    }
    #pragma unroll
    for (int mi = 0; mi < 2; ++mi)
        #pragma unroll
        for (int nj = 0; nj < 4; ++nj)
            #pragma unroll
            for (int r = 0; r < 4; ++r) {
                const int row = row0 + wm * 32 + mi * 16 + (l >> 4) * 4 + r;
                const int col = col0 + wn * 64 + nj * 16 + (l & 15);
                C[(size_t)row * MCOLS + col] = acc[mi][nj][r];
            }
}

// ---------------- K3: selection via sorting networks; outputs dense W[2048,256]
__device__ const unsigned short CAND_TBL[32] = {
    0x0100, 0x0302, 0x0504, 0x0706, 0x0908, 0x0B0A, 0x0D0C, 0x0F0E,
    0x1110, 0x1312, 0x1514, 0x1716,
    0x2120, 0x2322, 0x3024, 0x3231, 0x4033, 0x4241,
    0x5150, 0x6160, 0x7170,
    0x9080, 0xB0A0, 0xD0C0, 0xF0E0,
    0xFFFF, 0xFFFF, 0xFFFF, 0xFFFF, 0xFFFF, 0xFFFF, 0xFFFF
};

__device__ __forceinline__ float sel16(const float a[16], int i) {
    float b0 = (i & 1) ? a[1] : a[0];
    float b1 = (i & 1) ? a[3] : a[2];
    float b2 = (i & 1) ? a[5] : a[4];
    float b3 = (i & 1) ? a[7] : a[6];
    float b4 = (i & 1) ? a[9] : a[8];
    float b5 = (i & 1) ? a[11] : a[10];
    float b6 = (i & 1) ? a[13] : a[12];
    float b7 = (i & 1) ? a[15] : a[14];
    float c0 = (i & 2) ? b1 : b0;
    float c1 = (i & 2) ? b3 : b2;
    float c2 = (i & 2) ? b5 : b4;
    float c3 = (i & 2) ? b7 : b6;
    float d0 = (i & 4) ? c1 : c0;
    float d1 = (i & 4) ? c3 : c2;
    return (i & 8) ? d1 : d0;
}

__global__ __launch_bounds__(256) void k3_sel(const float* __restrict__ sim,
                                              float* __restrict__ W) {
    __shared__ unsigned long long ckey[8][50];
    __shared__ float winval[8][16];
    __shared__ int winflat[8][16];
    __shared__ int Wrow[256];

    const int tid = threadIdx.x;
    const int n = blockIdx.x;
    const int h = tid >> 5;
    const int lam = tid & 15;
    const int p = (tid >> 4) & 1;

    Wrow[tid] = 0;

    const float* s = sim + (size_t)n * MCOLS + p * 2048 + h * 256 + lam * 16;
    float v[16];
    #pragma unroll
    for (int c = 0; c < 4; ++c) {
        float4 t = *reinterpret_cast<const float4*>(s + c * 4);
        v[c * 4 + 0] = t.x; v[c * 4 + 1] = t.y; v[c * 4 + 2] = t.z; v[c * 4 + 3] = t.w;
    }

    #pragma unroll
    for (int k = 2; k <= 16; k <<= 1)
        #pragma unroll
        for (int j = k >> 1; j > 0; j >>= 1)
            #pragma unroll
            for (int i = 0; i < 16; ++i) {
                const int l2 = i ^ j;
                if (l2 > i) {
                    const bool asc = ((i & k) == 0);
                    const float lo = fminf(v[i], v[l2]), hi = fmaxf(v[i], v[l2]);
                    v[i] = asc ? lo : hi;
                    v[l2] = asc ? hi : lo;
                }
            }

    #pragma unroll
    for (int lvl = 1; lvl <= 8; lvl <<= 1) {
        float m[16];
        #pragma unroll
        for (int q = 0; q < 16; ++q)
            m[q] = fmaxf(v[q], __shfl_xor(v[15 - q], lvl));
        #pragma unroll
        for (int j = 8; j > 0; j >>= 1)
            #pragma unroll
            for (int i = 0; i < 16; ++i) {
                const int l2 = i ^ j;
                if (l2 > i) {
                    const float lo = fminf(m[i], m[l2]), hi = fmaxf(m[i], m[l2]);
                    m[i] = lo; m[l2] = hi;
                }
            }
        #pragma unroll
        for (int q = 0; q < 16; ++q) v[q] = m[q];
    }

    float other[16];
    #pragma unroll
    for (int q = 0; q < 16; ++q) other[q] = __shfl_xor(v[q], 16);
    const bool isP1 = (tid & 16) != 0;
    float sxd[16], syd[16];
    #pragma unroll
    for (int q = 0; q < 16; ++q) {
        const float own = v[15 - q], oth = other[15 - q];
        sxd[q] = isP1 ? oth : own;
        syd[q] = isP1 ? own : oth;
    }

    const int lc = tid & 31;
    const unsigned int cw = CAND_TBL[lc];
    unsigned long long mykey[2]; float myval[2]; int myflat[2]; int myrank[2] = {0, 0};
    #pragma unroll
    for (int u = 0; u < 2; ++u) {
        const int fl = (cw >> (8 * u)) & 0xFF;
        const float sv = sel16(sxd, fl >> 4) + sel16(syd, fl & 15);
        const unsigned int uv = __float_as_uint(sv);
        const unsigned int mo = (uv & 0x80000000u) ? ~uv : (uv | 0x80000000u);
        mykey[u] = ((unsigned long long)mo << 8) | (unsigned long long)(255 - fl);
        myval[u] = sv; myflat[u] = fl;
        const int slot = lc * 2 + u;
        if (slot < 50) ckey[h][slot] = mykey[u];
    }
    __syncthreads();
    for (int kk = 0; kk < 50; ++kk) {
        const unsigned long long ok = ckey[h][kk];
        myrank[0] += (ok > mykey[0]) ? 1 : 0;
        myrank[1] += (ok > mykey[1]) ? 1 : 0;
    }
    #pragma unroll
    for (int u = 0; u < 2; ++u)
        if (myrank[u] < 16) { winval[h][myrank[u]] = myval[u]; winflat[h][myrank[u]] = myflat[u]; }
    __syncthreads();

    if (!(tid & 16)) {
        const float sc = winval[h][lam];
        const float m0 = winval[h][0];
        float e = expf(sc - m0);
        float esum = e;
        #pragma unroll
        for (int off = 1; off < 16; off <<= 1) esum += __shfl_xor(esum, off);
        const int fl = winflat[h][lam];
        const float hv = sim[(size_t)n * MCOLS + QCOLS + fl];
        const float g = 0.5f * hv * (1.0f + erff(hv * 0.70710678118654752f));
        const float w = (e / esum) * g;
        atomicAdd(&Wrow[fl], __float2int_rn(w * 4194304.0f));
    }
    __syncthreads();
    W[(size_t)n * 256 + tid] = (float)Wrow[tid] * (1.0f / 4194304.0f);
}

// ---------------- K5: out[2048,512] = W[2048,256] @ up[0:256,512]  (fp32 VALU)
__global__ __launch_bounds__(256) void k5_out(const float* __restrict__ W,
                                              const float* __restrict__ up,
                                              float* __restrict__ out) {
    __shared__ float As[16][64];
    __shared__ float Bs[16][64];
    const int row0 = blockIdx.x * 64;
    const int col0 = blockIdx.y * 64;
    const int tid = threadIdx.x;
    const int ar = tid >> 2, ak = (tid & 3) * 4;
    const int bk = tid >> 4, bc = (tid & 15) * 4;
    const int tr = tid >> 4, tc = tid & 15;
    float acc[4][4] = {};
    for (int k0 = 0; k0 < 256; k0 += 16) {
        float4 av = *reinterpret_cast<const float4*>(&W[(size_t)(row0 + ar) * 256 + k0 + ak]);
        float4 bv = *reinterpret_cast<const float4*>(&up[(size_t)(k0 + bk) * NDIM + col0 + bc]);
        __syncthreads();
        As[ak + 0][ar] = av.x; As[ak + 1][ar] = av.y; As[ak + 2][ar] = av.z; As[ak + 3][ar] = av.w;
        *reinterpret_cast<float4*>(&Bs[bk][bc]) = bv;
        __syncthreads();
        #pragma unroll
        for (int kk = 0; kk < 16; ++kk) {
            float4 a = *(const float4*)&As[kk][tr * 4];
            float4 b = *(const float4*)&Bs[kk][tc * 4];
            float aa[4] = {a.x, a.y, a.z, a.w}, bb[4] = {b.x, b.y, b.z, b.w};
            #pragma unroll
            for (int i = 0; i < 4; ++i)
                #pragma unroll
                for (int j = 0; j < 4; ++j) acc[i][j] += aa[i] * bb[j];
        }
    }
    #pragma unroll
    for (int i = 0; i < 4; ++i) {
        float4 o = {acc[i][0], acc[i][1], acc[i][2], acc[i][3]};
        *reinterpret_cast<float4*>(&out[(size_t)(row0 + tr * 4 + i) * NDIM + col0 + tc * 4]) = o;
    }
}

extern "C" void kernel_launch(void* const* d_in, const int* in_sizes, int n_in,
                              void* d_out, int out_size, void* d_ws, size_t ws_size,
                              hipStream_t stream) {
    const float* x    = (const float*)d_in[0];
    const float* Wq   = (const float*)d_in[1];
    const float* keys = (const float*)d_in[2];
    const float* down = (const float*)d_in[3];
    const float* up   = (const float*)d_in[4];
    float* out = (float*)d_out;

    char* ws = (char*)d_ws;
    unsigned short* Mth = (unsigned short*)(ws);                       // 4352*512*2 = 4,456,448
    unsigned short* Mtl = (unsigned short*)(ws + 4456448);             // 4,456,448
    unsigned short* xh  = (unsigned short*)(ws + 8912896);             // 2,097,152
    unsigned short* xl  = (unsigned short*)(ws + 11010048);            // 2,097,152
    float* sim          = (float*)(ws + 13107200);                     // 35,651,584
    float* W            = (float*)(ws + 48758784);                     // 2,097,152

    kPrep<<<1280, 256, 0, stream>>>(x, down, xh, xl, Mth, Mtl);
    k1_combine<<<dim3(8, 4, 16), 256, 0, stream>>>(Wq, keys, Mth, Mtl);
    k2_mfma<<<dim3(32, 34), 256, 0, stream>>>(xh, xl, Mth, Mtl, sim);
    k3_sel<<<2048, 256, 0, stream>>>(sim, W);
    k5_out<<<dim3(32, 8), 256, 0, stream>>>(W, up, out);
}

// Round 6
// 105.241 us; speedup vs baseline: 3.4113x; 1.0711x over previous
//
#include <hip/hip_runtime.h>
#include <math.h>

#define N_TOK 2048
#define NDIM 512
#define HEADS 8
#define TOPK 16
#define QCOLS 4096   // similarity columns
#define MCOLS 4352   // 4096 sim cols + 256 D cols (x . down256 appended)

typedef __attribute__((ext_vector_type(8))) _Float16 f16x8;
typedef __attribute__((ext_vector_type(4))) float f32x4;

__device__ __forceinline__ unsigned short f32_to_f16(float f) {
    _Float16 h = (_Float16)f;
    return __builtin_bit_cast(unsigned short, h);
}
__device__ __forceinline__ float f16_to_f32(unsigned short u) {
    return (float)__builtin_bit_cast(_Float16, u);
}
__device__ __forceinline__ void gl_lds16(const void* g, void* l) {
    __builtin_amdgcn_global_load_lds(
        (const __attribute__((address_space(1))) void*)g,
        (__attribute__((address_space(3))) void*)l, 16, 0, 0);
}

// ---------------- kPrep: (a) split x -> xh+xl fp16; (b) down rows -> Mt rows 4096.. as fp16 hi/lo
__global__ __launch_bounds__(256) void kPrep(const float* __restrict__ x,
                                             const float* __restrict__ down,
                                             unsigned short* __restrict__ xh,
                                             unsigned short* __restrict__ xl,
                                             unsigned short* __restrict__ Mth,
                                             unsigned short* __restrict__ Mtl) {
    const int bid = blockIdx.x;
    const int tid = threadIdx.x;
    if (bid < 1024) {               // x split: one float4 per thread
        const int i = bid * 256 + tid;
        float4 v = reinterpret_cast<const float4*>(x)[i];
        float vv[4] = {v.x, v.y, v.z, v.w};
        ushort4 h, lo;
        unsigned short* hp = &h.x; unsigned short* lp = &lo.x;
        #pragma unroll
        for (int t = 0; t < 4; ++t) {
            unsigned short hh = f32_to_f16(vv[t]);
            hp[t] = hh;
            lp[t] = f32_to_f16(vv[t] - f16_to_f32(hh));
        }
        reinterpret_cast<ushort4*>(xh)[i] = h;
        reinterpret_cast<ushort4*>(xl)[i] = lo;
    } else {                        // down row e -> Mt row 4096+e (fp16 hi/lo)
        const int e = bid - 1024;   // 0..255
        const int d0 = tid * 2;
        float2 v = *reinterpret_cast<const float2*>(&down[(size_t)e * NDIM + d0]);
        ushort2 h, lo;
        unsigned short h0 = f32_to_f16(v.x);
        unsigned short h1 = f32_to_f16(v.y);
        h.x = h0; h.y = h1;
        lo.x = f32_to_f16(v.x - f16_to_f32(h0));
        lo.y = f32_to_f16(v.y - f16_to_f32(h1));
        *reinterpret_cast<ushort2*>(&Mth[(size_t)(QCOLS + e) * NDIM + d0]) = h;
        *reinterpret_cast<ushort2*>(&Mtl[(size_t)(QCOLS + e) * NDIM + d0]) = lo;
    }
}

// ---------------- K1: M[c, col] = sum_d Wq[c, off+d] * keys[h,k,p,d]  (fp32 VALU),
// written TRANSPOSED as fp16 hi/lo: Mth/Mtl[col][c]. Register-prefetch pipelined.
__global__ __launch_bounds__(256) void k1_combine(const float* __restrict__ Wq,
                                                  const float* __restrict__ keys,
                                                  unsigned short* __restrict__ Mth,
                                                  unsigned short* __restrict__ Mtl) {
    __shared__ float As[16][64];
    __shared__ float Bs[16][64];
    const int ph = blockIdx.z;       // p*8 + h
    const int p = ph >> 3, h = ph & 7;
    const int off = p * 2048 + h * 256;
    const int c0 = blockIdx.x * 64;
    const int k0 = blockIdx.y * 64;
    const int tid = threadIdx.x;
    const int lr = tid >> 2;
    const int ld4 = (tid & 3) * 4;
    const int tr = tid >> 4, tc = tid & 15;
    float acc[4][4] = {};
    const float* ap = &Wq[(size_t)(c0 + lr) * QCOLS + off + ld4];
    const float* bp = &keys[(size_t)((h * 256 + (k0 + lr)) * 2 + p) * 256 + ld4];
    float4 av = *reinterpret_cast<const float4*>(ap);
    float4 bv = *reinterpret_cast<const float4*>(bp);
    for (int d0 = 0; d0 < 256; d0 += 16) {
        __syncthreads();
        As[ld4 + 0][lr] = av.x; As[ld4 + 1][lr] = av.y; As[ld4 + 2][lr] = av.z; As[ld4 + 3][lr] = av.w;
        Bs[ld4 + 0][lr] = bv.x; Bs[ld4 + 1][lr] = bv.y; Bs[ld4 + 2][lr] = bv.z; Bs[ld4 + 3][lr] = bv.w;
        __syncthreads();
        if (d0 + 16 < 256) {
            av = *reinterpret_cast<const float4*>(ap + d0 + 16);
            bv = *reinterpret_cast<const float4*>(bp + d0 + 16);
        }
        #pragma unroll
        for (int kk = 0; kk < 16; ++kk) {
            float4 a = *reinterpret_cast<const float4*>(&As[kk][tr * 4]);
            float4 b = *reinterpret_cast<const float4*>(&Bs[kk][tc * 4]);
            float aa[4] = {a.x, a.y, a.z, a.w}, bb[4] = {b.x, b.y, b.z, b.w};
            #pragma unroll
            for (int i = 0; i < 4; ++i)
                #pragma unroll
                for (int j = 0; j < 4; ++j) acc[i][j] += aa[i] * bb[j];
        }
    }
    #pragma unroll
    for (int j = 0; j < 4; ++j) {
        const int col = off + k0 + tc * 4 + j;
        ushort4 h4, l4;
        unsigned short* hp = &h4.x; unsigned short* lp = &l4.x;
        #pragma unroll
        for (int i = 0; i < 4; ++i) {
            float v = acc[i][j];
            unsigned short hh = f32_to_f16(v);
            hp[i] = hh;
            lp[i] = f32_to_f16(v - f16_to_f32(hh));
        }
        *reinterpret_cast<ushort4*>(&Mth[(size_t)col * NDIM + c0 + tr * 4]) = h4;
        *reinterpret_cast<ushort4*>(&Mtl[(size_t)col * NDIM + c0 + tr * 4]) = l4;
    }
}

// ---------------- K2: sim = xh*Mh + xh*Ml + xl*Mh, fp16 3-term split.
// BK=32, double-buffered LDS (2 x 24KB), ONE barrier per K-step: stage(next)
// issued before compute(cur) so load latency hides under MFMA+ds_read.
// LDS row layout: [hi 64B | lo 64B] = 128B rows, XOR-swizzled (2-way, free).
#define BM 64
#define BN 128
#define BK 32
#define ABYTES 8192      // 64 rows * 128B
#define BBYTES 16384     // 128 rows * 128B
#define BUFBYTES 24576
__global__ __launch_bounds__(256, 3) void k2_mfma(const unsigned short* __restrict__ xh,
                                                  const unsigned short* __restrict__ xl,
                                                  const unsigned short* __restrict__ Mth,
                                                  const unsigned short* __restrict__ Mtl,
                                                  float* __restrict__ C) {
    __shared__ __align__(16) char lds[2 * BUFBYTES];   // 48 KB
    const int tid = threadIdx.x;
    const int w = tid >> 6, l = tid & 63;
    const int row0 = blockIdx.x * BM;
    const int col0 = blockIdx.y * BN;
    const int wm = w >> 1, wn = w & 1;     // wave tile: 32 x 64
    f32x4 acc[2][4] = {};

    // staging: linear LDS dest (wave-uniform base + lane*16), inverse-swizzled source
    auto stage = [&](int buf, int s) {
        const int kk = s * BK;
        char* base = lds + buf * BUFBYTES;
        #pragma unroll
        for (int t = 0; t < 2; ++t) {                 // A tile: 8 KB
            const int q = w * 2048 + t * 1024 + l * 16;
            const int r = q >> 7;
            const int bsw = (q & 127) ^ ((r & 7) << 4);
            const unsigned short* src = (bsw < 64)
                ? xh + (size_t)(row0 + r) * NDIM + kk + (bsw >> 1)
                : xl + (size_t)(row0 + r) * NDIM + kk + ((bsw - 64) >> 1);
            gl_lds16(src, base + w * 2048 + t * 1024);
        }
        #pragma unroll
        for (int t = 0; t < 4; ++t) {                 // B tile: 16 KB
            const int q = w * 4096 + t * 1024 + l * 16;
            const int r = q >> 7;
            const int bsw = (q & 127) ^ ((r & 7) << 4);
            const unsigned short* src = (bsw < 64)
                ? Mth + (size_t)(col0 + r) * NDIM + kk + (bsw >> 1)
                : Mtl + (size_t)(col0 + r) * NDIM + kk + ((bsw - 64) >> 1);
            gl_lds16(src, base + ABYTES + w * 4096 + t * 1024);
        }
    };

    stage(0, 0);
    __syncthreads();
    for (int s = 0; s < 16; ++s) {
        if (s + 1 < 16) stage((s + 1) & 1, s + 1);
        const char* base = lds + (s & 1) * BUFBYTES;
        const int bq = (l >> 4) * 16;                  // lane's 16B k-slot
        f16x8 ah[2], al[2], bh[4], bl[4];
        #pragma unroll
        for (int mi = 0; mi < 2; ++mi) {
            const int ra = wm * 32 + mi * 16 + (l & 15);
            const int swz = (ra & 7) << 4;
            ah[mi] = *(const f16x8*)(base + ra * 128 + (bq ^ swz));
            al[mi] = *(const f16x8*)(base + ra * 128 + ((bq + 64) ^ swz));
        }
        #pragma unroll
        for (int nj = 0; nj < 4; ++nj) {
            const int rb = wn * 64 + nj * 16 + (l & 15);
            const int swz = (rb & 7) << 4;
            bh[nj] = *(const f16x8*)(base + ABYTES + rb * 128 + (bq ^ swz));
            bl[nj] = *(const f16x8*)(base + ABYTES + rb * 128 + ((bq + 64) ^ swz));
        }
        #pragma unroll
        for (int mi = 0; mi < 2; ++mi)
            #pragma unroll
            for (int nj = 0; nj < 4; ++nj) {
                acc[mi][nj] = __builtin_amdgcn_mfma_f32_16x16x32_f16(ah[mi], bh[nj], acc[mi][nj], 0, 0, 0);
                acc[mi][nj] = __builtin_amdgcn_mfma_f32_16x16x32_f16(ah[mi], bl[nj], acc[mi][nj], 0, 0, 0);
                acc[mi][nj] = __builtin_amdgcn_mfma_f32_16x16x32_f16(al[mi], bh[nj], acc[mi][nj], 0, 0, 0);
            }
        __syncthreads();   // drains vmcnt (next-buf stage) + protects cur buf reuse
    }
    #pragma unroll
    for (int mi = 0; mi < 2; ++mi)
        #pragma unroll
        for (int nj = 0; nj < 4; ++nj)
            #pragma unroll
            for (int r = 0; r < 4; ++r) {
                const int row = row0 + wm * 32 + mi * 16 + (l >> 4) * 4 + r;
                const int col = col0 + wn * 64 + nj * 16 + (l & 15);
                C[(size_t)row * MCOLS + col] = acc[mi][nj][r];
            }
}

// ---------------- K3: selection via sorting networks; outputs dense W[2048,256]
__device__ const unsigned short CAND_TBL[32] = {
    0x0100, 0x0302, 0x0504, 0x0706, 0x0908, 0x0B0A, 0x0D0C, 0x0F0E,
    0x1110, 0x1312, 0x1514, 0x1716,
    0x2120, 0x2322, 0x3024, 0x3231, 0x4033, 0x4241,
    0x5150, 0x6160, 0x7170,
    0x9080, 0xB0A0, 0xD0C0, 0xF0E0,
    0xFFFF, 0xFFFF, 0xFFFF, 0xFFFF, 0xFFFF, 0xFFFF, 0xFFFF
};

__device__ __forceinline__ float sel16(const float a[16], int i) {
    float b0 = (i & 1) ? a[1] : a[0];
    float b1 = (i & 1) ? a[3] : a[2];
    float b2 = (i & 1) ? a[5] : a[4];
    float b3 = (i & 1) ? a[7] : a[6];
    float b4 = (i & 1) ? a[9] : a[8];
    float b5 = (i & 1) ? a[11] : a[10];
    float b6 = (i & 1) ? a[13] : a[12];
    float b7 = (i & 1) ? a[15] : a[14];
    float c0 = (i & 2) ? b1 : b0;
    float c1 = (i & 2) ? b3 : b2;
    float c2 = (i & 2) ? b5 : b4;
    float c3 = (i & 2) ? b7 : b6;
    float d0 = (i & 4) ? c1 : c0;
    float d1 = (i & 4) ? c3 : c2;
    return (i & 8) ? d1 : d0;
}

__global__ __launch_bounds__(256) void k3_sel(const float* __restrict__ sim,
                                              float* __restrict__ W) {
    __shared__ unsigned long long ckey[8][50];
    __shared__ float winval[8][16];
    __shared__ int winflat[8][16];
    __shared__ int Wrow[256];

    const int tid = threadIdx.x;
    const int n = blockIdx.x;
    const int h = tid >> 5;
    const int lam = tid & 15;
    const int p = (tid >> 4) & 1;

    Wrow[tid] = 0;

    const float* s = sim + (size_t)n * MCOLS + p * 2048 + h * 256 + lam * 16;
    float v[16];
    #pragma unroll
    for (int c = 0; c < 4; ++c) {
        float4 t = *reinterpret_cast<const float4*>(s + c * 4);
        v[c * 4 + 0] = t.x; v[c * 4 + 1] = t.y; v[c * 4 + 2] = t.z; v[c * 4 + 3] = t.w;
    }

    #pragma unroll
    for (int k = 2; k <= 16; k <<= 1)
        #pragma unroll
        for (int j = k >> 1; j > 0; j >>= 1)
            #pragma unroll
            for (int i = 0; i < 16; ++i) {
                const int l2 = i ^ j;
                if (l2 > i) {
                    const bool asc = ((i & k) == 0);
                    const float lo = fminf(v[i], v[l2]), hi = fmaxf(v[i], v[l2]);
                    v[i] = asc ? lo : hi;
                    v[l2] = asc ? hi : lo;
                }
            }

    #pragma unroll
    for (int lvl = 1; lvl <= 8; lvl <<= 1) {
        float m[16];
        #pragma unroll
        for (int q = 0; q < 16; ++q)
            m[q] = fmaxf(v[q], __shfl_xor(v[15 - q], lvl));
        #pragma unroll
        for (int j = 8; j > 0; j >>= 1)
            #pragma unroll
            for (int i = 0; i < 16; ++i) {
                const int l2 = i ^ j;
                if (l2 > i) {
                    const float lo = fminf(m[i], m[l2]), hi = fmaxf(m[i], m[l2]);
                    m[i] = lo; m[l2] = hi;
                }
            }
        #pragma unroll
        for (int q = 0; q < 16; ++q) v[q] = m[q];
    }

    float other[16];
    #pragma unroll
    for (int q = 0; q < 16; ++q) other[q] = __shfl_xor(v[q], 16);
    const bool isP1 = (tid & 16) != 0;
    float sxd[16], syd[16];
    #pragma unroll
    for (int q = 0; q < 16; ++q) {
        const float own = v[15 - q], oth = other[15 - q];
        sxd[q] = isP1 ? oth : own;
        syd[q] = isP1 ? own : oth;
    }

    const int lc = tid & 31;
    const unsigned int cw = CAND_TBL[lc];
    unsigned long long mykey[2]; float myval[2]; int myflat[2]; int myrank[2] = {0, 0};
    #pragma unroll
    for (int u = 0; u < 2; ++u) {
        const int fl = (cw >> (8 * u)) & 0xFF;
        const float sv = sel16(sxd, fl >> 4) + sel16(syd, fl & 15);
        const unsigned int uv = __float_as_uint(sv);
        const unsigned int mo = (uv & 0x80000000u) ? ~uv : (uv | 0x80000000u);
        mykey[u] = ((unsigned long long)mo << 8) | (unsigned long long)(255 - fl);
        myval[u] = sv; myflat[u] = fl;
        const int slot = lc * 2 + u;
        if (slot < 50) ckey[h][slot] = mykey[u];
    }
    __syncthreads();
    for (int kk = 0; kk < 50; ++kk) {
        const unsigned long long ok = ckey[h][kk];
        myrank[0] += (ok > mykey[0]) ? 1 : 0;
        myrank[1] += (ok > mykey[1]) ? 1 : 0;
    }
    #pragma unroll
    for (int u = 0; u < 2; ++u)
        if (myrank[u] < 16) { winval[h][myrank[u]] = myval[u]; winflat[h][myrank[u]] = myflat[u]; }
    __syncthreads();

    if (!(tid & 16)) {
        const float sc = winval[h][lam];
        const float m0 = winval[h][0];
        float e = expf(sc - m0);
        float esum = e;
        #pragma unroll
        for (int off = 1; off < 16; off <<= 1) esum += __shfl_xor(esum, off);
        const int fl = winflat[h][lam];
        const float hv = sim[(size_t)n * MCOLS + QCOLS + fl];
        const float g = 0.5f * hv * (1.0f + erff(hv * 0.70710678118654752f));
        const float w = (e / esum) * g;
        atomicAdd(&Wrow[fl], __float2int_rn(w * 4194304.0f));
    }
    __syncthreads();
    W[(size_t)n * 256 + tid] = (float)Wrow[tid] * (1.0f / 4194304.0f);
}

// ---------------- K5: out[2048,512] = W[2048,256] @ up[0:256,512]  (fp32 VALU)
// 32x64 tiles -> 512 blocks (2/CU); register-prefetch pipelined.
__global__ __launch_bounds__(256) void k5_out(const float* __restrict__ W,
                                              const float* __restrict__ up,
                                              float* __restrict__ out) {
    __shared__ float As[16][32];
    __shared__ float Bs[16][64];
    const int row0 = blockIdx.x * 32;
    const int col0 = blockIdx.y * 64;
    const int tid = threadIdx.x;
    const int ar = tid & 31, ak = (tid >> 5) * 2;
    const int bk = tid >> 4, bc = (tid & 15) * 4;
    const int r0 = (tid >> 4) * 2, c0 = (tid & 15) * 4;
    float acc[2][4] = {};
    const float* wp = &W[(size_t)(row0 + ar) * 256 + ak];
    const float* up0 = &up[(size_t)bk * NDIM + col0 + bc];
    float2 a2 = *reinterpret_cast<const float2*>(wp);
    float4 b4 = *reinterpret_cast<const float4*>(up0);
    for (int k0 = 0; k0 < 256; k0 += 16) {
        __syncthreads();
        As[ak + 0][ar] = a2.x;
        As[ak + 1][ar] = a2.y;
        *reinterpret_cast<float4*>(&Bs[bk][bc]) = b4;
        __syncthreads();
        if (k0 + 16 < 256) {
            a2 = *reinterpret_cast<const float2*>(wp + k0 + 16);
            b4 = *reinterpret_cast<const float4*>(up0 + (size_t)16 * NDIM + (size_t)k0 * NDIM);
        }
        #pragma unroll
        for (int kk = 0; kk < 16; ++kk) {
            const float a0 = As[kk][r0], a1 = As[kk][r0 + 1];
            float4 b = *reinterpret_cast<const float4*>(&Bs[kk][c0]);
            float bb[4] = {b.x, b.y, b.z, b.w};
            #pragma unroll
            for (int j = 0; j < 4; ++j) {
                acc[0][j] += a0 * bb[j];
                acc[1][j] += a1 * bb[j];
            }
        }
    }
    #pragma unroll
    for (int i = 0; i < 2; ++i) {
        float4 o = {acc[i][0], acc[i][1], acc[i][2], acc[i][3]};
        *reinterpret_cast<float4*>(&out[(size_t)(row0 + r0 + i) * NDIM + col0 + c0]) = o;
    }
}

extern "C" void kernel_launch(void* const* d_in, const int* in_sizes, int n_in,
                              void* d_out, int out_size, void* d_ws, size_t ws_size,
                              hipStream_t stream) {
    const float* x    = (const float*)d_in[0];
    const float* Wq   = (const float*)d_in[1];
    const float* keys = (const float*)d_in[2];
    const float* down = (const float*)d_in[3];
    const float* up   = (const float*)d_in[4];
    float* out = (float*)d_out;

    char* ws = (char*)d_ws;
    unsigned short* Mth = (unsigned short*)(ws);                       // 4352*512*2 = 4,456,448
    unsigned short* Mtl = (unsigned short*)(ws + 4456448);             // 4,456,448
    unsigned short* xh  = (unsigned short*)(ws + 8912896);             // 2,097,152
    unsigned short* xl  = (unsigned short*)(ws + 11010048);            // 2,097,152
    float* sim          = (float*)(ws + 13107200);                     // 35,651,584
    float* W            = (float*)(ws + 48758784);                     // 2,097,152

    kPrep<<<1280, 256, 0, stream>>>(x, down, xh, xl, Mth, Mtl);
    k1_combine<<<dim3(8, 4, 16), 256, 0, stream>>>(Wq, keys, Mth, Mtl);
    k2_mfma<<<dim3(32, 34), 256, 0, stream>>>(xh, xl, Mth, Mtl, sim);
    k3_sel<<<2048, 256, 0, stream>>>(sim, W);
    k5_out<<<dim3(64, 8), 256, 0, stream>>>(W, up, out);
}